// Round 11
// baseline (84.220 us; speedup 1.0000x reference)
//
#include <hip/hip_runtime.h>
#include <hip/hip_bf16.h>
#include <math.h>

#define NPAIR 4096       // N = B*S
#define D 128
#define TWO_N 8192
// Rb rows pre-scaled by ALPHA = sqrt(2*log2(e)): MFMA acc == 2*log2(e)*sim,
// so exp(2*sim) == exp2(acc) -> a single raw v_exp_f32 in the epilogue.
#define ALPHA 1.6986436f

typedef float f32x4 __attribute__((ext_vector_type(4)));
typedef long lx2 __attribute__((ext_vector_type(2)));

__device__ __forceinline__ void async_ld16(void* lds, const void* g) {
    // async global->LDS DMA, 16B/lane; LDS dest = wave-uniform base + lane*16
    __builtin_amdgcn_global_load_lds(
        (__attribute__((address_space(1))) const unsigned int*)g,
        (__attribute__((address_space(3))) unsigned int*)lds, 16, 0, 0);
}

// 1024 blocks x 256 threads; wave w handles pair-row k = blockIdx*4 + w.
// Emits ALPHA-scaled fp8 e4m3 rows in q-grouped layout: chunk c (global k
// [c*8,c*8+8)) stored at byte (c&3)*32 + (c>>2)*8 -> each MFMA lane's 4
// K-chunks are 32 contiguous bytes. pos[] stays exact fp32.
// Also zero-inits rowsum[8192] and out[0] (simexp adds atomically).
__global__ __launch_bounds__(256) void norm_kernel(const float* __restrict__ zi,
                                                   const float* __restrict__ zj,
                                                   unsigned char* __restrict__ Rb,
                                                   float* __restrict__ pos,
                                                   float* __restrict__ rowsum,
                                                   float* __restrict__ out) {
    if (threadIdx.x < 8) rowsum[blockIdx.x * 8 + threadIdx.x] = 0.f;
    if (blockIdx.x == 0 && threadIdx.x == 8) out[0] = 0.f;
    int k = blockIdx.x * 4 + (threadIdx.x >> 6);
    int t = threadIdx.x & 63;                 // 2 elems each
    const float2 a = *(const float2*)(zi + k * D + 2 * t);
    const float2 b = *(const float2*)(zj + k * D + 2 * t);
    float si = a.x * a.x + a.y * a.y;
    float sj = b.x * b.x + b.y * b.y;
    float dt = a.x * b.x + a.y * b.y;
    #pragma unroll
    for (int m = 1; m < 64; m <<= 1) {
        si += __shfl_xor(si, m, 64);
        sj += __shfl_xor(sj, m, 64);
        dt += __shfl_xor(dt, m, 64);
    }
    float ii = 1.0f / fmaxf(sqrtf(si), 1e-12f);
    float ij = 1.0f / fmaxf(sqrtf(sj), 1e-12f);
    if (t == 0) pos[k] = dt * ii * ij;        // exact (unscaled) positive sim
    ii *= ALPHA; ij *= ALPHA;
    // elems e=2t,2t+1: chunk c = t>>2, byte = (c&3)*32 + (c>>2)*8 + 2*(t&3)
    int c = t >> 2;
    int posb = (c & 3) * 32 + (c >> 2) * 8 + 2 * (t & 3);
    int r0 = __builtin_amdgcn_cvt_pk_fp8_f32(a.x * ii, a.y * ii, 0, false);
    *(unsigned short*)(Rb + (size_t)k * 128 + posb) = (unsigned short)r0;
    int r1 = __builtin_amdgcn_cvt_pk_fp8_f32(b.x * ij, b.y * ij, 0, false);
    *(unsigned short*)(Rb + (size_t)(k + NPAIR) * 128 + posb) = (unsigned short)r1;
}

// SYMMETRIC TRIANGLE, streamed. sim_q = Rq*Rq^T is exactly symmetric (same
// quantized operands), so each off-diag 64x64 tile contributes row-sums to
// stripe i AND col-sums to stripe j (one computation, two uses) -> all pipes
// halve. Balance: stripe bi pairs with 127-bi -> exactly 129 tiles/pair;
// block = (pair, jc of 16) takes a contiguous 8-9 tile chunk of the list
// coltile(idx) = idx<nA ? bi+idx : idx-1 (nA = 128-bi); diag at idx in {0,nA}.
// R9 mechanics kept: zero barriers, wave-private 2KB panels, triple buffer,
// depth-2 prefetch, vmcnt(2) mid-loop, fp8 MFMA, raw v_exp_f32 epilogue.
// Col-sums: 1 reg/tile (lane's 16 accs share a col), atomics deferred past
// the loop so the in-loop vmcnt queue stays pure panel-DMAs.
__global__ __launch_bounds__(256, 4) void simexp_kernel(const unsigned char* __restrict__ Rb,
                                                        float* __restrict__ rowsum) {
    __shared__ uint4 Bs[4][3][128];      // [wave][buf][16 cols x 8 pieces] 2KB/buf
    const int pair = blockIdx.x >> 4;    // 0..63
    const int jc = blockIdx.x & 15;      // 0..15
    const int biA = pair, biB = 127 - pair;
    const int nA = 128 - biA;
    const int start = (jc * 129) >> 4;
    const int end = ((jc + 1) * 129) >> 4;
    const int n = end - start;           // 8 or 9

    const int tid = threadIdx.x;
    const int wave = tid >> 6, lane = tid & 63;
    const int rp = lane & 15, q = lane >> 4;

    long afr[4][4];                      // [kt][rt] fp8 A fragments
    auto loadA = [&](int s) {
        const unsigned char* Ab = Rb + (size_t)(s * 64 + rp) * 128 + q * 32;
        #pragma unroll
        for (int rt = 0; rt < 4; ++rt) {
            lx2 h0 = *(const lx2*)(Ab + rt * 16 * 128);
            lx2 h1 = *(const lx2*)(Ab + rt * 16 * 128 + 16);
            afr[0][rt] = h0.x;  afr[1][rt] = h0.y;
            afr[2][rt] = h1.x;  afr[3][rt] = h1.y;
        }
    };
    auto coltile = [&](int idx) { return (idx < nA) ? (biA + idx) : (idx - 1); };

    char* lpanel = (char*)&Bs[wave][0][0];
    const int laneoff = (lane >> 3) * 128 + (((lane & 7) ^ ((lane >> 3) & 7)) << 4);
    auto prefetch_tile = [&](int ct, int buf) {
        const unsigned char* g = Rb + (size_t)(ct * 64 + wave * 16) * 128 + laneoff;
        async_ld16(lpanel + buf * 2048, g);
        async_ld16(lpanel + buf * 2048 + 1024, g + 1024);
    };

    float rs[16];
    #pragma unroll
    for (int i = 0; i < 16; ++i) rs[i] = 0.f;
    auto flush_rows = [&](int s) {       // rs -> rowsum[stripe s], reset rs
        #pragma unroll
        for (int i = 0; i < 16; ++i) {
            float v = rs[i];
            v += __shfl_xor(v, 1, 64);
            v += __shfl_xor(v, 2, 64);
            v += __shfl_xor(v, 4, 64);
            v += __shfl_xor(v, 8, 64);
            if (rp == 0)
                atomicAdd(&rowsum[s * 64 + (i >> 2) * 16 + q * 4 + (i & 3)], v);
            rs[i] = 0.f;
        }
    };

    loadA(start < nA ? biA : biB);
    prefetch_tile(coltile(start), 0);
    prefetch_tile(coltile(start + 1), 1);

    float csum[9];
    const int slot0 = rp * 8, sw = rp & 7;

    #pragma unroll
    for (int i = 0; i < 9; ++i) {
        if (i >= n) break;
        const int idx = start + i;
        if (i > 0 && idx == nA) {        // phase crossing: stripe A -> stripe B
            flush_rows(biA);
            loadA(biB);
        }
        // Wait only for the oldest panel; next stays in flight.
        if (i + 1 < n) __builtin_amdgcn_s_waitcnt(0x0F72);   // vmcnt(2)
        else           __builtin_amdgcn_s_waitcnt(0x0F70);   // vmcnt(0)

        const uint4* P = &Bs[wave][i % 3][0];
        lx2 v0 = *(const lx2*)&P[slot0 + ((q * 2 + 0) ^ sw)];  // kt0, kt1
        lx2 v1 = *(const lx2*)&P[slot0 + ((q * 2 + 1) ^ sw)];  // kt2, kt3

        if (i + 2 < n) prefetch_tile(coltile(idx + 2), (i + 2) % 3);

        f32x4 acc[4] = {};
        #pragma unroll
        for (int rt = 0; rt < 4; ++rt) {
            acc[rt] = __builtin_amdgcn_mfma_f32_16x16x32_fp8_fp8(afr[0][rt], v0.x, acc[rt], 0, 0, 0);
            acc[rt] = __builtin_amdgcn_mfma_f32_16x16x32_fp8_fp8(afr[1][rt], v0.y, acc[rt], 0, 0, 0);
            acc[rt] = __builtin_amdgcn_mfma_f32_16x16x32_fp8_fp8(afr[2][rt], v1.x, acc[rt], 0, 0, 0);
            acc[rt] = __builtin_amdgcn_mfma_f32_16x16x32_fp8_fp8(afr[3][rt], v1.y, acc[rt], 0, 0, 0);
        }

        // D layout: col(tile-local) = wave*16 + rp (lane-constant!),
        //           row = rt*16 + q*4 + r
        float cs = 0.f;
        if (idx == 0 || idx == nA) {     // diagonal tile: rows only, skip ro==co
            #pragma unroll
            for (int rt = 0; rt < 4; ++rt)
                #pragma unroll
                for (int r = 0; r < 4; ++r) {
                    int ro = rt * 16 + q * 4 + r;
                    int co = wave * 16 + rp;
                    float e = __builtin_amdgcn_exp2f(acc[rt][r]);
                    rs[rt * 4 + r] += (ro == co) ? 0.f : e;
                }
        } else {
            #pragma unroll
            for (int rt = 0; rt < 4; ++rt)
                #pragma unroll
                for (int r = 0; r < 4; ++r) {
                    float e = __builtin_amdgcn_exp2f(acc[rt][r]);
                    rs[rt * 4 + r] += e;
                    cs += e;
                }
        }
        csum[i] = cs;
    }

    flush_rows((end - 1 < nA) ? biA : biB);

    // Deferred col-sum atomics (symmetric contribution to stripe j rows).
    #pragma unroll
    for (int i = 0; i < 9; ++i) {
        if (i >= n) break;
        const int idx = start + i;
        if (idx == 0 || idx == nA) continue;     // diag tiles: no col pass
        float v = csum[i];
        v += __shfl_xor(v, 16, 64);
        v += __shfl_xor(v, 32, 64);
        if (q == 0)
            atomicAdd(&rowsum[coltile(idx) * 64 + wave * 16 + rp], v);
    }
}

// 16 blocks x 256 threads; each thread does 2 rows; one atomicAdd per block.
__global__ __launch_bounds__(256) void finalize_kernel(const float* __restrict__ rowsum,
                                                       const float* __restrict__ pos,
                                                       float* __restrict__ out) {
    __shared__ float red[4];
    int tid = threadIdx.x;
    float local = 0.f;
    #pragma unroll
    for (int i = 0; i < 2; ++i) {
        int k = blockIdx.x * 512 + i * 256 + tid;
        float ps = pos[k & (NPAIR - 1)];
        float p2 = ps + ps;
        local += logf(rowsum[k] + __expf(p2)) - p2;
    }
    #pragma unroll
    for (int m = 1; m < 64; m <<= 1) local += __shfl_xor(local, m, 64);
    if ((tid & 63) == 0) red[tid >> 6] = local;
    __syncthreads();
    if (tid == 0) {
        float s = red[0] + red[1] + red[2] + red[3];
        atomicAdd(out, s * (1.0f / (float)TWO_N));
    }
}

extern "C" void kernel_launch(void* const* d_in, const int* in_sizes, int n_in,
                              void* d_out, int out_size, void* d_ws, size_t ws_size,
                              hipStream_t stream) {
    const float* zi = (const float*)d_in[0];
    const float* zj = (const float*)d_in[1];
    char* ws = (char*)d_ws;
    unsigned char* Rb = (unsigned char*)ws;                         // 1 MB fp8 rows
    float* rowsum = (float*)(ws + 1024 * 1024);                     // 32 KB
    float* pos = (float*)(ws + 1024 * 1024 + 32 * 1024);            // 16 KB

    norm_kernel<<<NPAIR / 4, 256, 0, stream>>>(zi, zj, Rb, pos, rowsum, (float*)d_out);
    simexp_kernel<<<64 * 16, 256, 0, stream>>>(Rb, rowsum);
    finalize_kernel<<<16, 256, 0, stream>>>(rowsum, pos, (float*)d_out);
}

// Round 12
// 76.419 us; speedup vs baseline: 1.1021x; 1.1021x over previous
//
#include <hip/hip_runtime.h>
#include <hip/hip_bf16.h>
#include <math.h>

#define NPAIR 4096       // N = B*S
#define D 128
#define TWO_N 8192
#define NSLAB 32         // 8 jc-slabs x 4 waves, race-free partial rows
// Rb rows pre-scaled by ALPHA = sqrt(2*log2(e)): MFMA acc == 2*log2(e)*sim,
// so exp(2*sim) == exp2(acc) -> a single raw v_exp_f32 in the epilogue.
#define ALPHA 1.6986436f

typedef float f32x4 __attribute__((ext_vector_type(4)));
typedef int i32x8 __attribute__((ext_vector_type(8)));

__device__ __forceinline__ void async_ld16(void* lds, const void* g) {
    // async global->LDS DMA, 16B/lane; LDS dest = wave-uniform base + lane*16
    __builtin_amdgcn_global_load_lds(
        (__attribute__((address_space(1))) const unsigned int*)g,
        (__attribute__((address_space(3))) unsigned int*)lds, 16, 0, 0);
}

__device__ __forceinline__ i32x8 mk8(uint4 lo, uint4 hi) {
    return (i32x8){(int)lo.x, (int)lo.y, (int)lo.z, (int)lo.w,
                   (int)hi.x, (int)hi.y, (int)hi.z, (int)hi.w};
}

// 1024 blocks x 256 threads; wave w handles pair-row k = blockIdx*4 + w.
// Emits ALPHA-scaled fp8 e4m3 rows, PLAIN ROW-MAJOR (byte b = element b):
// the x128 scaled MFMA wants each lane k-contiguous [q*32, q*32+32).
// pos[] stays exact fp32. Zero-inits out[0].
__global__ __launch_bounds__(256) void norm_kernel(const float* __restrict__ zi,
                                                   const float* __restrict__ zj,
                                                   unsigned char* __restrict__ Rb,
                                                   float* __restrict__ pos,
                                                   float* __restrict__ out) {
    if (blockIdx.x == 0 && threadIdx.x == 0) out[0] = 0.f;
    int k = blockIdx.x * 4 + (threadIdx.x >> 6);
    int t = threadIdx.x & 63;                 // 2 elems each
    const float2 a = *(const float2*)(zi + k * D + 2 * t);
    const float2 b = *(const float2*)(zj + k * D + 2 * t);
    float si = a.x * a.x + a.y * a.y;
    float sj = b.x * b.x + b.y * b.y;
    float dt = a.x * b.x + a.y * b.y;
    #pragma unroll
    for (int m = 1; m < 64; m <<= 1) {
        si += __shfl_xor(si, m, 64);
        sj += __shfl_xor(sj, m, 64);
        dt += __shfl_xor(dt, m, 64);
    }
    float ii = 1.0f / fmaxf(sqrtf(si), 1e-12f);
    float ij = 1.0f / fmaxf(sqrtf(sj), 1e-12f);
    if (t == 0) pos[k] = dt * ii * ij;        // exact (unscaled) positive sim
    ii *= ALPHA; ij *= ALPHA;
    int r0 = __builtin_amdgcn_cvt_pk_fp8_f32(a.x * ii, a.y * ii, 0, false);
    *(unsigned short*)(Rb + (size_t)k * 128 + 2 * t) = (unsigned short)r0;
    int r1 = __builtin_amdgcn_cvt_pk_fp8_f32(b.x * ij, b.y * ij, 0, false);
    *(unsigned short*)(Rb + (size_t)(k + NPAIR) * 128 + 2 * t) = (unsigned short)r1;
}

// R9 structure + MX-scaled fp8 MFMA (K=128 in ONE instruction, 2x rate).
// 1024 blocks: bi = b>>3 (64-row stripe), jc = b&7 (1024-col slab, 16 jt
// tiles of 64 cols). ZERO BARRIERS: wave-private 16-col panels (2KB) stream
// through a TRIPLE buffer (24KB/block -> 4 blocks/CU, one resident round),
// prefetched two jt ahead; loop-top wait = vmcnt(2). Scales = 1.0 (e8m0
// 0x7F): per-lane scale byte covers k-block q = lane>>4, matching the
// k-contiguous per-lane data fragment. Raw v_exp_f32 epilogue.
__global__ __launch_bounds__(256, 4) void simexp_kernel(const unsigned char* __restrict__ Rb,
                                                        float* __restrict__ rspart) {
    __shared__ uint4 Bs[4][3][128];      // [wave][buf][16 cols x 8 pieces] 2KB/buf
    const int bi = blockIdx.x >> 3;      // 0..127 (64-row stripe)
    const int jc = blockIdx.x & 7;       // 0..7  (1024-col slab)
    const int tid = threadIdx.x;
    const int wave = tid >> 6, lane = tid & 63;
    const int rp = lane & 15, q = lane >> 4;

    // A fragments: row = bi*64 + rt*16 + rp; lane's k [q*32, q*32+32).
    i32x8 afr[4];                        // [rt]
    {
        const unsigned char* Ab = Rb + (size_t)(bi * 64 + rp) * 128 + q * 32;
        #pragma unroll
        for (int rt = 0; rt < 4; ++rt) {
            uint4 h0 = *(const uint4*)(Ab + rt * 16 * 128);
            uint4 h1 = *(const uint4*)(Ab + rt * 16 * 128 + 16);
            afr[rt] = mk8(h0, h1);
        }
    }

    // Wave-private B panel: cols jc*1024 + jt*64 + wave*16 + [0,16), 128B/col,
    // 2 DMAs/jt (8 cols each). DMA d, lane l: col cr = d*8 + (l>>3), stored
    // piece p' = l&7, global piece p = p' ^ (cr&7)  [slot = cr*8 + (p^(cr&7))].
    const unsigned char* gslab = Rb + (size_t)(jc * 1024 + wave * 16) * 128;
    char* lpanel = (char*)&Bs[wave][0][0];
    const int laneoff = (lane >> 3) * 128 + (((lane & 7) ^ ((lane >> 3) & 7)) << 4);

    float rs[16];
    #pragma unroll
    for (int i = 0; i < 16; ++i) rs[i] = 0.f;

    // prefetch jt=0 (buf0) and jt=1 (buf1): 4 DMAs outstanding
    #pragma unroll
    for (int j = 0; j < 2; ++j)
        #pragma unroll
        for (int d = 0; d < 2; ++d)
            async_ld16(lpanel + j * 2048 + d * 1024,
                       gslab + j * 8192 + d * 1024 + laneoff);

    const int diagbase = bi * 64 - jc * 1024;   // diag col offset in slab
    const int slot0 = rp * 8;
    const int sw = rp & 7;

    #pragma unroll
    for (int jt = 0; jt < 16; ++jt) {
        // Wait only for the OLDEST panel (this jt's 2 DMAs); next stays in flight.
        if (jt < 14) __builtin_amdgcn_s_waitcnt(0x0F72);   // vmcnt(2)
        else         __builtin_amdgcn_s_waitcnt(0x0F70);   // vmcnt(0)

        const int cur = jt % 3;
        const uint4* P = &Bs[wave][cur][0];
        // lane needs col rp pieces 2q (k low half) and 2q+1 (k high half)
        uint4 u0 = P[slot0 + ((q * 2 + 0) ^ sw)];
        uint4 u1 = P[slot0 + ((q * 2 + 1) ^ sw)];
        i32x8 bfr = mk8(u0, u1);

        if (jt < 14) {                   // prefetch jt+2 into buf (jt+2)%3
            const int nb = (jt + 2) % 3;
            #pragma unroll
            for (int d = 0; d < 2; ++d)
                async_ld16(lpanel + nb * 2048 + d * 1024,
                           gslab + (jt + 2) * 8192 + d * 1024 + laneoff);
        }

        f32x4 acc[4] = {};
        #pragma unroll
        for (int rt = 0; rt < 4; ++rt)
            acc[rt] = __builtin_amdgcn_mfma_scale_f32_16x16x128_f8f6f4(
                afr[rt], bfr, acc[rt],
                0, 0,                     // cbsz=fp8(e4m3), blgp=fp8(e4m3)
                0, 0x7F7F7F7F,            // A scale opsel, scale = 1.0
                0, 0x7F7F7F7F);           // B scale opsel, scale = 1.0

        // D layout: col(tile-local) = wave*16 + rp, row = rt*16 + q*4 + r
        if (jt * 64 == diagbase) {       // the one jt tile holding the diagonal
            #pragma unroll
            for (int rt = 0; rt < 4; ++rt)
                #pragma unroll
                for (int r = 0; r < 4; ++r) {
                    int ro = rt * 16 + q * 4 + r;
                    int co = wave * 16 + rp;
                    float e = __builtin_amdgcn_exp2f(acc[rt][r]);
                    rs[rt * 4 + r] += (ro == co) ? 0.f : e;
                }
        } else {
            #pragma unroll
            for (int rt = 0; rt < 4; ++rt)
                #pragma unroll
                for (int r = 0; r < 4; ++r)
                    rs[rt * 4 + r] += __builtin_amdgcn_exp2f(acc[rt][r]);
        }
    }

    // Reduce each reg across the 16 rp lanes; rp==0 stores its 16 rows.
    #pragma unroll
    for (int i = 0; i < 16; ++i) {
        float v = rs[i];
        v += __shfl_xor(v, 1, 64);
        v += __shfl_xor(v, 2, 64);
        v += __shfl_xor(v, 4, 64);
        v += __shfl_xor(v, 8, 64);
        rs[i] = v;
    }
    if (rp == 0) {
        const int slab = jc * 4 + wave;
        const int rowb = bi * 64 + q * 4;
        #pragma unroll
        for (int rt = 0; rt < 4; ++rt)
            #pragma unroll
            for (int r = 0; r < 4; ++r)
                rspart[slab * TWO_N + rowb + rt * 16 + r] = rs[rt * 4 + r];
    }
}

// 16 blocks x 256 threads; each thread does 2 rows; one atomicAdd per block.
__global__ __launch_bounds__(256) void finalize_kernel(const float* __restrict__ rspart,
                                                       const float* __restrict__ pos,
                                                       float* __restrict__ out) {
    __shared__ float red[4];
    int tid = threadIdx.x;
    float local = 0.f;
    #pragma unroll
    for (int i = 0; i < 2; ++i) {
        int k = blockIdx.x * 512 + i * 256 + tid;
        float rsum = 0.f;
        #pragma unroll
        for (int p = 0; p < NSLAB; ++p) rsum += rspart[p * TWO_N + k];
        float ps = pos[k & (NPAIR - 1)];
        float p2 = ps + ps;
        local += logf(rsum + __expf(p2)) - p2;
    }
    #pragma unroll
    for (int m = 1; m < 64; m <<= 1) local += __shfl_xor(local, m, 64);
    if ((tid & 63) == 0) red[tid >> 6] = local;
    __syncthreads();
    if (tid == 0) {
        float s = red[0] + red[1] + red[2] + red[3];
        atomicAdd(out, s * (1.0f / (float)TWO_N));
    }
}

extern "C" void kernel_launch(void* const* d_in, const int* in_sizes, int n_in,
                              void* d_out, int out_size, void* d_ws, size_t ws_size,
                              hipStream_t stream) {
    const float* zi = (const float*)d_in[0];
    const float* zj = (const float*)d_in[1];
    char* ws = (char*)d_ws;
    unsigned char* Rb = (unsigned char*)ws;                         // 1 MB fp8 rows
    float* rspart = (float*)(ws + 1 * 1024 * 1024);                 // 32*8192*4 = 1 MB
    float* pos = (float*)(ws + 2 * 1024 * 1024);                    // 16 KB

    norm_kernel<<<NPAIR / 4, 256, 0, stream>>>(zi, zj, Rb, pos, (float*)d_out);
    simexp_kernel<<<128 * 8, 256, 0, stream>>>(Rb, rspart);
    finalize_kernel<<<16, 256, 0, stream>>>(rspart, pos, (float*)d_out);
}